// Round 1
// baseline (120.038 us; speedup 1.0000x reference)
//
#include <hip/hip_runtime.h>
#include <stdint.h>

// Problem constants
#define BDIM 128
#define NIN 512
#define UNITS 512
#define NB 16
#define KDIM (NIN * NB)          // 8192
#define KSPLIT 8
#define KRANGE (KDIM / KSPLIT)   // 1024
#define BK 64
#define TILE_N 128

typedef unsigned short ushort_t;
typedef __attribute__((ext_vector_type(8))) short short8v;   // 8 x bf16 (4 VGPRs)
typedef __attribute__((ext_vector_type(4))) float f32x4;     // MFMA accumulator

// ws layout:
//   A_all : 16*128*8192 bf16 = 32 MiB  @ 0
//   Wb    : 512*8192   bf16 =  8 MiB  @ 32 MiB
//   P     : 8*16*128*512 f32 = 32 MiB @ 40 MiB
#define A_ELEMS (16u * 128u * 8192u)
#define W_ELEMS (512u * 8192u)
#define P_OFF_BYTES ((size_t)(A_ELEMS + W_ELEMS) * 2u)
#define WS_NEEDED (P_OFF_BYTES + (size_t)8 * 16 * 128 * 512 * 4)

__device__ __forceinline__ float ga_sign(int a, int b) {
  int t = a >> 1, sw = 0;
  while (t) { sw += __popc(t & b); t >>= 1; }
  return (sw & 1) ? -1.0f : 1.0f;
}

__device__ __forceinline__ ushort_t f2bf(float f) {
  unsigned u = __float_as_uint(f);
  u = (u + 0x7FFFu + ((u >> 16) & 1u)) >> 16;   // RNE
  return (ushort_t)u;
}

// ---------------------------------------------------------------------------
// prep: A_all[k][b][n*16+j] = bf16(x[b,n,j^k] * s(j^k, j));  Wb[u][n*16+j] = bf16(w[u,n,j])
// ---------------------------------------------------------------------------
#define A_TH (16 * 128 * 512)          // 1,048,576
#define PREP_TOT (A_TH + 512 * 512)    // 1,310,720  -> 5120 blocks of 256

__global__ __launch_bounds__(256) void prep_kernel(const float* __restrict__ x,
                                                   const float* __restrict__ w,
                                                   ushort_t* __restrict__ A,
                                                   ushort_t* __restrict__ Wb) {
  int tid = blockIdx.x * 256 + threadIdx.x;
  if (tid < A_TH) {
    int n = tid & 511;
    int b = (tid >> 9) & 127;
    int k = tid >> 16;
    const float4* xp = (const float4*)(x + ((size_t)(b * 512 + n)) * 16);
    float xv[16];
#pragma unroll
    for (int q = 0; q < 4; q++) {
      float4 v = xp[q];
      xv[q * 4 + 0] = v.x; xv[q * 4 + 1] = v.y;
      xv[q * 4 + 2] = v.z; xv[q * 4 + 3] = v.w;
    }
    ushort_t o[16];
#pragma unroll
    for (int j = 0; j < 16; j++) {
      int i = j ^ k;
      o[j] = f2bf(xv[i] * ga_sign(i, j));
    }
    ushort_t* dst = A + ((size_t)(k * 128 + b) * 8192 + n * 16);
    ((uint4*)dst)[0] = *(const uint4*)&o[0];
    ((uint4*)dst)[1] = *(const uint4*)&o[8];
  } else {
    int t = tid - A_TH;          // < 262144
    int n = t & 511;
    int u = t >> 9;
    const float4* wp = (const float4*)(w + ((size_t)(u * 512 + n)) * 16);
    ushort_t o[16];
#pragma unroll
    for (int q = 0; q < 4; q++) {
      float4 v = wp[q];
      o[q * 4 + 0] = f2bf(v.x); o[q * 4 + 1] = f2bf(v.y);
      o[q * 4 + 2] = f2bf(v.z); o[q * 4 + 3] = f2bf(v.w);
    }
    ushort_t* dst = Wb + ((size_t)u * 8192 + n * 16);
    ((uint4*)dst)[0] = *(const uint4*)&o[0];
    ((uint4*)dst)[1] = *(const uint4*)&o[8];
  }
}

// ---------------------------------------------------------------------------
// gemm: per (kblade, split, u-tile): C += A_k[:, krange] * W[u-tile, krange]^T
// 128x128 tile, BK=64, global_load_lds(16B) staging, 16x16x32 bf16 MFMA.
// LDS slot(m,kk8) = m*8 + (kk8 ^ (m&7))  -- coalesced staging AND ~conflict-free frags.
// Partials: P[split][kblade][m][u]  (u contiguous -> coalesced stores)
// ---------------------------------------------------------------------------
__global__ __launch_bounds__(256) void gemm_kernel(const ushort_t* __restrict__ Aall,
                                                   const ushort_t* __restrict__ Wb,
                                                   float* __restrict__ P) {
  __shared__ __align__(16) ushort_t smem[16384];   // As[0..8191] | Bs[8192..16383]

  const int kblade = blockIdx.x >> 3;
  const int split  = blockIdx.x & 7;
  const int u0     = blockIdx.y * TILE_N;

  const int wv   = threadIdx.x >> 6;
  const int lane = threadIdx.x & 63;

  const ushort_t* Ab = Aall + (size_t)(kblade * 128) * 8192 + split * KRANGE;
  const ushort_t* Bb = Wb + (size_t)u0 * 8192 + split * KRANGE;

  // staging: per-lane global element offsets for 4 instructions (64 slots each)
  int off[4];
#pragma unroll
  for (int it = 0; it < 4; it++) {
    int s = wv * 256 + it * 64 + lane;   // slot 0..1023
    int m = s >> 3;
    int p = s & 7;
    int kk8 = p ^ (m & 7);
    off[it] = m * 8192 + kk8 * 8;
  }

  f32x4 acc[4][4];
#pragma unroll
  for (int i = 0; i < 4; i++)
#pragma unroll
    for (int j = 0; j < 4; j++)
      acc[i][j] = (f32x4){0.f, 0.f, 0.f, 0.f};

  const int wm = (wv & 1) * 64;
  const int wn = (wv >> 1) * 64;
  const int q  = lane >> 4;
  const int la = lane & 15;

  for (int kt = 0; kt < KRANGE / BK; kt++) {
#pragma unroll
    for (int it = 0; it < 4; it++) {
      int ldsbase = (wv * 256 + it * 64) * 8;   // ushort index (slot*8)
      __builtin_amdgcn_global_load_lds(
          (const __attribute__((address_space(1))) unsigned int*)(Ab + off[it] + kt * BK),
          (__attribute__((address_space(3))) unsigned int*)(&smem[ldsbase]),
          16, 0, 0);
      __builtin_amdgcn_global_load_lds(
          (const __attribute__((address_space(1))) unsigned int*)(Bb + off[it] + kt * BK),
          (__attribute__((address_space(3))) unsigned int*)(&smem[8192 + ldsbase]),
          16, 0, 0);
    }
    __syncthreads();

#pragma unroll
    for (int kk = 0; kk < 2; kk++) {
      short8v av[4], bv[4];
      int kk8 = kk * 4 + q;
#pragma unroll
      for (int f = 0; f < 4; f++) {
        int m = wm + f * 16 + la;
        int slota = m * 8 + (kk8 ^ (m & 7));
        av[f] = *(const short8v*)(&smem[slota * 8]);
        int n = wn + f * 16 + la;
        int slotb = n * 8 + (kk8 ^ (n & 7));
        bv[f] = *(const short8v*)(&smem[8192 + slotb * 8]);
      }
#pragma unroll
      for (int f = 0; f < 4; f++)
#pragma unroll
        for (int g = 0; g < 4; g++)
          acc[f][g] = __builtin_amdgcn_mfma_f32_16x16x32_bf16(av[f], bv[g], acc[f][g], 0, 0, 0);
    }
    __syncthreads();
  }

  // epilogue: P[((split*16+kblade)*128 + row)*512 + u0 + col]
  float* Pb = P + (size_t)((split * 16 + kblade) * 128) * 512 + u0;
#pragma unroll
  for (int f = 0; f < 4; f++) {
#pragma unroll
    for (int g = 0; g < 4; g++) {
#pragma unroll
      for (int r = 0; r < 4; r++) {
        int row = wm + f * 16 + q * 4 + r;     // C/D: row = quad*4 + reg (m89-verified)
        int col = wn + g * 16 + la;            //      col = lane&15
        Pb[(size_t)row * 512 + col] = acc[f][g][r];
      }
    }
  }
}

// ---------------------------------------------------------------------------
// reduce: out[b,u,k] = bias[u,k] + sum_s P[s][k][b][u]
// ---------------------------------------------------------------------------
__global__ __launch_bounds__(256) void reduce_kernel(const float* __restrict__ P,
                                                     const float* __restrict__ bias,
                                                     float* __restrict__ out) {
  int t = blockIdx.x * 256 + threadIdx.x;   // 65536 threads: (b,u)
  int u = t & 511;
  int b = t >> 9;
  float acc[16];
#pragma unroll
  for (int k = 0; k < 16; k++) acc[k] = bias[u * 16 + k];
  for (int s = 0; s < 8; s++) {
#pragma unroll
    for (int k = 0; k < 16; k++)
      acc[k] += P[((size_t)(s * 16 + k) * 128 + b) * 512 + u];
  }
  float* op = out + ((size_t)(b * 512 + u)) * 16;
#pragma unroll
  for (int qq = 0; qq < 4; qq++)
    ((float4*)op)[qq] = make_float4(acc[qq * 4 + 0], acc[qq * 4 + 1],
                                    acc[qq * 4 + 2], acc[qq * 4 + 3]);
}

// ---------------------------------------------------------------------------
// fallback (only if ws too small): exact fp32, slow but correct
// ---------------------------------------------------------------------------
__global__ __launch_bounds__(256) void naive_kernel(const float* __restrict__ x,
                                                    const float* __restrict__ w,
                                                    const float* __restrict__ bias,
                                                    float* __restrict__ out) {
  int t = blockIdx.x * 256 + threadIdx.x;
  if (t >= 128 * 512 * 16) return;
  int k = t & 15;
  int u = (t >> 4) & 511;
  int b = t >> 13;
  float sgn[16];
#pragma unroll
  for (int i = 0; i < 16; i++) sgn[i] = ga_sign(i, i ^ k);
  float acc = bias[u * 16 + k];
  for (int n = 0; n < 512; n++) {
    const float* xp = x + ((size_t)(b * 512 + n)) * 16;
    const float* wp = w + ((size_t)(u * 512 + n)) * 16;
#pragma unroll
    for (int i = 0; i < 16; i++)
      acc += xp[i] * sgn[i] * wp[i ^ k];
  }
  out[t] = acc;
}

extern "C" void kernel_launch(void* const* d_in, const int* in_sizes, int n_in,
                              void* d_out, int out_size, void* d_ws, size_t ws_size,
                              hipStream_t stream) {
  const float* x    = (const float*)d_in[0];
  const float* w    = (const float*)d_in[1];
  const float* bias = (const float*)d_in[2];
  float* out = (float*)d_out;

  if (ws_size >= WS_NEEDED && d_ws != nullptr) {
    ushort_t* A  = (ushort_t*)d_ws;
    ushort_t* Wb = A + A_ELEMS;
    float* P = (float*)((char*)d_ws + P_OFF_BYTES);

    prep_kernel<<<PREP_TOT / 256, 256, 0, stream>>>(x, w, A, Wb);
    gemm_kernel<<<dim3(128, 4), 256, 0, stream>>>(A, Wb, P);
    reduce_kernel<<<256, 256, 0, stream>>>(P, bias, out);
  } else {
    naive_kernel<<<(128 * 512 * 16) / 256, 256, 0, stream>>>(x, w, bias, out);
  }
}

// Round 2
// 102.332 us; speedup vs baseline: 1.1730x; 1.1730x over previous
//
#include <hip/hip_runtime.h>
#include <stdint.h>

typedef unsigned short ushort_t;
typedef __attribute__((ext_vector_type(8))) short short8v;   // 8 x bf16
typedef __attribute__((ext_vector_type(4))) float f32x4;     // MFMA acc

#define NSPLIT 8

// ws layout: At bf16 [16][128][512] (2 MiB) | Wt bf16 [16][512][512] (8 MiB) | P f32 [8][16][128][512] (32 MiB)
#define AT_ELEMS (16u * 128u * 512u)
#define WT_ELEMS (16u * 512u * 512u)
#define P_OFF_BYTES ((size_t)(AT_ELEMS + WT_ELEMS) * 2u)
#define P_ELEMS ((size_t)NSPLIT * 16 * 128 * 512)
#define WS_NEEDED (P_OFF_BYTES + P_ELEMS * 4u)

__host__ __device__ constexpr int ga_sign_i(int a, int b) {
  int t = a >> 1, sw = 0;
  while (t) {
    int x = t & b;
    while (x) { sw += x & 1; x >>= 1; }
    t >>= 1;
  }
  return (sw & 1) ? -1 : 1;
}

struct SignTab { int s[16][16]; };
constexpr SignTab make_tab() {
  SignTab t{};
  for (int i = 0; i < 16; i++)
    for (int j = 0; j < 16; j++) t.s[i][j] = ga_sign_i(i, j);
  return t;
}
constexpr SignTab STAB = make_tab();

__device__ __forceinline__ ushort_t f2bf(float f) {
  unsigned u = __float_as_uint(f);
  u = (u + 0x7FFFu + ((u >> 16) & 1u)) >> 16;   // RNE
  return (ushort_t)u;
}

__device__ __forceinline__ short8v neg_bf16x8(short8v v) {
  const short m = (short)0x8000;
  return v ^ (short8v){m, m, m, m, m, m, m, m};
}

// ---------------------------------------------------------------------------
// prep: At[j][b][n] = bf16(x[b,n,j]);  Wt[j][u][n] = bf16(w[u,n,j])
// ---------------------------------------------------------------------------
#define PREP_XT (128 * 512)
#define PREP_TOT (PREP_XT + 512 * 512)   // 327,680 -> 1280 blocks

__global__ __launch_bounds__(256) void prep_kernel(const float* __restrict__ x,
                                                   const float* __restrict__ w,
                                                   ushort_t* __restrict__ At,
                                                   ushort_t* __restrict__ Wt) {
  int tid = blockIdx.x * 256 + threadIdx.x;
  if (tid < PREP_XT) {
    int n = tid & 511, b = tid >> 9;
    const float4* xp = (const float4*)(x + (size_t)tid * 16);
    float v[16];
#pragma unroll
    for (int qq = 0; qq < 4; qq++) {
      float4 t = xp[qq];
      v[qq * 4 + 0] = t.x; v[qq * 4 + 1] = t.y; v[qq * 4 + 2] = t.z; v[qq * 4 + 3] = t.w;
    }
#pragma unroll
    for (int j = 0; j < 16; j++)
      At[((size_t)(j * 128 + b)) * 512 + n] = f2bf(v[j]);   // lanes: consecutive n -> coalesced
  } else {
    int t = tid - PREP_XT;
    int n = t & 511, u = t >> 9;
    const float4* wp = (const float4*)(w + (size_t)t * 16);
    float v[16];
#pragma unroll
    for (int qq = 0; qq < 4; qq++) {
      float4 tt = wp[qq];
      v[qq * 4 + 0] = tt.x; v[qq * 4 + 1] = tt.y; v[qq * 4 + 2] = tt.z; v[qq * 4 + 3] = tt.w;
    }
#pragma unroll
    for (int j = 0; j < 16; j++)
      Wt[((size_t)(j * 512 + u)) * 512 + n] = f2bf(v[j]);
  }
}

// ---------------------------------------------------------------------------
// gemm: block = (32 b) x (32 u) x (all 16 k), n-split 8 (n-range 64 = 2 chunks of 32).
// LDS 64 KB: Xs[16j][32b][32n] | Ws[16j][32u][32n], 64B rows, 16B chunks XOR-swizzled:
//   content chunk q stored at position q ^ (r&3) ^ ((r>>2)&3)   (DMA-compatible, 2-way banks)
// Wave W handles k = 4W + kl. i = j^k = 4(jh^W) + (jl^kl): per jh-group, cache the
// 4 matching x-frag pairs; sign s(i,j) is compile-time in the <W>-specialized body.
// ---------------------------------------------------------------------------
template <int W>
__device__ __forceinline__ void compute_chunk(const char* sm, int lbx,
                                              f32x4 (&acc)[4][2][2]) {
#pragma unroll
  for (int jh = 0; jh < 4; jh++) {
    const int ig = jh ^ W;
    short8v av[4][2], bv[4][2];
#pragma unroll
    for (int il = 0; il < 4; il++)
#pragma unroll
      for (int f = 0; f < 2; f++)
        av[il][f] = *(const short8v*)(sm + ((ig * 4 + il) * 32 + f * 16) * 64 + lbx);
#pragma unroll
    for (int jl = 0; jl < 4; jl++)
#pragma unroll
      for (int g = 0; g < 2; g++)
        bv[jl][g] = *(const short8v*)(sm + 32768 + ((jh * 4 + jl) * 32 + g * 16) * 64 + lbx);
#pragma unroll
    for (int kl = 0; kl < 4; kl++) {
#pragma unroll
      for (int jl = 0; jl < 4; jl++) {
        const int il = jl ^ kl;
        const int i = ig * 4 + il;          // compile-time after unroll
        const int j = jh * 4 + jl;
        short8v a0 = av[il][0], a1 = av[il][1];
        if (STAB.s[i][j] < 0) { a0 = neg_bf16x8(a0); a1 = neg_bf16x8(a1); }
        acc[kl][0][0] = __builtin_amdgcn_mfma_f32_16x16x32_bf16(a0, bv[jl][0], acc[kl][0][0], 0, 0, 0);
        acc[kl][0][1] = __builtin_amdgcn_mfma_f32_16x16x32_bf16(a0, bv[jl][1], acc[kl][0][1], 0, 0, 0);
        acc[kl][1][0] = __builtin_amdgcn_mfma_f32_16x16x32_bf16(a1, bv[jl][0], acc[kl][1][0], 0, 0, 0);
        acc[kl][1][1] = __builtin_amdgcn_mfma_f32_16x16x32_bf16(a1, bv[jl][1], acc[kl][1][1], 0, 0, 0);
      }
    }
  }
}

__global__ __launch_bounds__(256, 2) void gemm_kernel(const ushort_t* __restrict__ At,
                                                      const ushort_t* __restrict__ Wt,
                                                      float* __restrict__ P) {
  __shared__ __align__(16) ushort_t smem[32768];   // 64 KB

  const int ut = blockIdx.x;       // 0..15
  const int bt = blockIdx.y;       // 0..3
  const int sp = blockIdx.z;       // 0..7
  const int u0 = ut * 32, b0 = bt * 32, n0 = sp * 64;

  const int wv = threadIdx.x >> 6;
  const int lane = threadIdx.x & 63;

  // staging source offsets (element units), swizzle baked in
  int offX[8], offW[8];
#pragma unroll
  for (int it = 0; it < 8; it++) {
    int slot = it * 256 + wv * 64 + lane;          // 0..2047
    int r = slot >> 2, p = slot & 3;
    int q = p ^ (r & 3) ^ ((r >> 2) & 3);
    offX[it] = ((r >> 5) * 128 + (r & 31)) * 512 + q * 8;   // j=r>>5, bl=r&31
    offW[it] = ((r >> 5) * 512 + (r & 31)) * 512 + q * 8;   // j=r>>5, ul=r&31
  }
  const ushort_t* Ax = At + (size_t)b0 * 512 + n0;
  const ushort_t* Wx = Wt + (size_t)u0 * 512 + n0;

  const int la = lane & 15, q = lane >> 4;
  const int lbx = la * 64 + (q ^ (la & 3) ^ ((la >> 2) & 3)) * 16;  // frag byte offset in row-block

  f32x4 acc[4][2][2];
#pragma unroll
  for (int a = 0; a < 4; a++)
#pragma unroll
    for (int f = 0; f < 2; f++)
#pragma unroll
      for (int g = 0; g < 2; g++) acc[a][f][g] = (f32x4){0.f, 0.f, 0.f, 0.f};

  const char* sm = (const char*)smem;

#pragma unroll 1
  for (int kt = 0; kt < 2; kt++) {
#pragma unroll
    for (int it = 0; it < 8; it++)
      __builtin_amdgcn_global_load_lds(
          (const __attribute__((address_space(1))) unsigned int*)(Ax + offX[it] + kt * 32),
          (__attribute__((address_space(3))) unsigned int*)(&smem[(it * 256 + wv * 64) * 8]),
          16, 0, 0);
#pragma unroll
    for (int it = 0; it < 8; it++)
      __builtin_amdgcn_global_load_lds(
          (const __attribute__((address_space(1))) unsigned int*)(Wx + offW[it] + kt * 32),
          (__attribute__((address_space(3))) unsigned int*)(&smem[16384 + (it * 256 + wv * 64) * 8]),
          16, 0, 0);
    __syncthreads();
    switch (wv) {
      case 0: compute_chunk<0>(sm, lbx, acc); break;
      case 1: compute_chunk<1>(sm, lbx, acc); break;
      case 2: compute_chunk<2>(sm, lbx, acc); break;
      default: compute_chunk<3>(sm, lbx, acc); break;
    }
    __syncthreads();
  }

  // epilogue: P[((sp*16 + k)*128 + b0+row)*512 + u0 + col], coalesced in col(=u)
  float* Pb = P + (size_t)sp * 16 * 128 * 512;
#pragma unroll
  for (int kl = 0; kl < 4; kl++) {
    int k = wv * 4 + kl;
#pragma unroll
    for (int f = 0; f < 2; f++)
#pragma unroll
      for (int g = 0; g < 2; g++)
#pragma unroll
        for (int r2 = 0; r2 < 4; r2++) {
          int row = b0 + f * 16 + q * 4 + r2;      // C/D: row = quad*4 + reg (m89)
          int col = u0 + g * 16 + la;              //      col = lane&15
          Pb[((size_t)(k * 128 + row)) * 512 + col] = acc[kl][f][g][r2];
        }
  }
}

// ---------------------------------------------------------------------------
// reduce: out[b,u,k] = bias[u,k] + sum_s P[s][k][b][u]
// ---------------------------------------------------------------------------
__global__ __launch_bounds__(256) void reduce_kernel(const float* __restrict__ P,
                                                     const float* __restrict__ bias,
                                                     float* __restrict__ out) {
  int t = blockIdx.x * 256 + threadIdx.x;   // 65536 threads: (b,u)
  int u = t & 511;
  int b = t >> 9;
  float acc[16];
#pragma unroll
  for (int k = 0; k < 16; k++) acc[k] = bias[u * 16 + k];
  for (int s = 0; s < NSPLIT; s++) {
#pragma unroll
    for (int k = 0; k < 16; k++)
      acc[k] += P[((size_t)(s * 16 + k) * 128 + b) * 512 + u];
  }
  float* op = out + ((size_t)(b * 512 + u)) * 16;
#pragma unroll
  for (int qq = 0; qq < 4; qq++)
    ((float4*)op)[qq] = make_float4(acc[qq * 4 + 0], acc[qq * 4 + 1],
                                    acc[qq * 4 + 2], acc[qq * 4 + 3]);
}

// ---------------------------------------------------------------------------
// fallback (ws too small): exact fp32, slow but correct
// ---------------------------------------------------------------------------
__global__ __launch_bounds__(256) void naive_kernel(const float* __restrict__ x,
                                                    const float* __restrict__ w,
                                                    const float* __restrict__ bias,
                                                    float* __restrict__ out) {
  int t = blockIdx.x * 256 + threadIdx.x;
  if (t >= 128 * 512 * 16) return;
  int k = t & 15;
  int u = (t >> 4) & 511;
  int b = t >> 13;
  float sgn[16];
#pragma unroll
  for (int i = 0; i < 16; i++) sgn[i] = (float)ga_sign_i(i, i ^ k);
  float acc = bias[u * 16 + k];
  for (int n = 0; n < 512; n++) {
    const float* xp = x + ((size_t)(b * 512 + n)) * 16;
    const float* wp = w + ((size_t)(u * 512 + n)) * 16;
#pragma unroll
    for (int i = 0; i < 16; i++)
      acc += xp[i] * sgn[i] * wp[i ^ k];
  }
  out[t] = acc;
}

extern "C" void kernel_launch(void* const* d_in, const int* in_sizes, int n_in,
                              void* d_out, int out_size, void* d_ws, size_t ws_size,
                              hipStream_t stream) {
  const float* x    = (const float*)d_in[0];
  const float* w    = (const float*)d_in[1];
  const float* bias = (const float*)d_in[2];
  float* out = (float*)d_out;

  if (ws_size >= WS_NEEDED && d_ws != nullptr) {
    ushort_t* At = (ushort_t*)d_ws;
    ushort_t* Wt = At + AT_ELEMS;
    float* P = (float*)((char*)d_ws + P_OFF_BYTES);

    prep_kernel<<<PREP_TOT / 256, 256, 0, stream>>>(x, w, At, Wt);
    gemm_kernel<<<dim3(16, 4, NSPLIT), 256, 0, stream>>>(At, Wt, P);
    reduce_kernel<<<256, 256, 0, stream>>>(P, bias, out);
  } else {
    naive_kernel<<<(128 * 512 * 16) / 256, 256, 0, stream>>>(x, w, bias, out);
  }
}